// Round 1
// baseline (128.312 us; speedup 1.0000x reference)
//
#include <hip/hip_runtime.h>

#define NPIX 4194304   // 64*256*256 per image
#define BATCH 4
#define MINK 1024ULL
#define NBINS 4096

typedef unsigned long long u64;

__device__ __forceinline__ float pix_loss(float v0, float v1, float v2, int t) {
    float m = fmaxf(fmaxf(v0, v1), v2);
    float lse = m + __logf(__expf(v0 - m) + __expf(v1 - m) + __expf(v2 - m));
    float xt = (t == 0) ? v0 : ((t == 1) ? v1 : v2);
    return lse - xt;
}

// K1: per-image {fg_sum, bg_sum, fg_cnt}
__global__ __launch_bounds__(256) void k_reduce(const float* __restrict__ x,
                                                const int* __restrict__ tg,
                                                double* __restrict__ fg_sum,
                                                double* __restrict__ bg_sum,
                                                u64* __restrict__ fg_cnt) {
    const int b = blockIdx.y;
    const float* xb = x + (size_t)b * 3 * NPIX;
    const int* tb = tg + (size_t)b * NPIX;
    float fs = 0.f, bs = 0.f;
    int fc = 0;
    const int stride = gridDim.x * blockDim.x * 4;
    for (int i = (blockIdx.x * blockDim.x + threadIdx.x) * 4; i < NPIX; i += stride) {
        const float4 a = *(const float4*)(xb + i);
        const float4 c = *(const float4*)(xb + NPIX + i);
        const float4 d = *(const float4*)(xb + 2 * NPIX + i);
        const int4 t4 = *(const int4*)(tb + i);
        float l;
        l = pix_loss(a.x, c.x, d.x, t4.x); if (t4.x > 0) { fs += l; fc++; } else bs += l;
        l = pix_loss(a.y, c.y, d.y, t4.y); if (t4.y > 0) { fs += l; fc++; } else bs += l;
        l = pix_loss(a.z, c.z, d.z, t4.z); if (t4.z > 0) { fs += l; fc++; } else bs += l;
        l = pix_loss(a.w, c.w, d.w, t4.w); if (t4.w > 0) { fs += l; fc++; } else bs += l;
    }
#pragma unroll
    for (int off = 32; off > 0; off >>= 1) {
        fs += __shfl_down(fs, off);
        bs += __shfl_down(bs, off);
        fc += __shfl_down(fc, off);
    }
    __shared__ float sfs[4], sbs[4];
    __shared__ int sfc[4];
    const int wid = threadIdx.x >> 6;
    if ((threadIdx.x & 63) == 0) { sfs[wid] = fs; sbs[wid] = bs; sfc[wid] = fc; }
    __syncthreads();
    if (threadIdx.x == 0) {
        atomicAdd(&fg_sum[b], (double)(sfs[0] + sfs[1] + sfs[2] + sfs[3]));
        atomicAdd(&bg_sum[b], (double)(sbs[0] + sbs[1] + sbs[2] + sbs[3]));
        atomicAdd(&fg_cnt[b], (u64)(sfc[0] + sfc[1] + sfc[2] + sfc[3]));
    }
}

// K2: histogram of bg losses (float-bit bins, order-preserving for x>=0).
// Early-exits when k == bg_num (the case for this data) -> costs only a launch.
__global__ __launch_bounds__(256) void k_hist(const float* __restrict__ x,
                                              const int* __restrict__ tg,
                                              const u64* __restrict__ fg_cnt,
                                              unsigned int* __restrict__ hist_cnt,
                                              float* __restrict__ hist_sum) {
    const int b = blockIdx.y;
    const u64 fc = fg_cnt[b];
    const u64 bg = (u64)NPIX - fc;
    u64 mk = fc > MINK ? fc : MINK;
    const u64 k = bg < mk ? bg : mk;
    if (k >= bg) return;  // top-k covers all bg: bg_sum suffices, no hist needed

    __shared__ unsigned int hc[NBINS];
    __shared__ float hs[NBINS];
    for (int i = threadIdx.x; i < NBINS; i += blockDim.x) { hc[i] = 0u; hs[i] = 0.f; }
    __syncthreads();

    const float* xb = x + (size_t)b * 3 * NPIX;
    const int* tb = tg + (size_t)b * NPIX;
    const int stride = gridDim.x * blockDim.x * 4;
    for (int i = (blockIdx.x * blockDim.x + threadIdx.x) * 4; i < NPIX; i += stride) {
        const float4 a = *(const float4*)(xb + i);
        const float4 c = *(const float4*)(xb + NPIX + i);
        const float4 d = *(const float4*)(xb + 2 * NPIX + i);
        const int4 t4 = *(const int4*)(tb + i);
        float v[4][3] = {{a.x, c.x, d.x}, {a.y, c.y, d.y}, {a.z, c.z, d.z}, {a.w, c.w, d.w}};
        int tt[4] = {t4.x, t4.y, t4.z, t4.w};
#pragma unroll
        for (int j = 0; j < 4; ++j) {
            if (tt[j] == 0) {
                float l = fmaxf(pix_loss(v[j][0], v[j][1], v[j][2], tt[j]), 0.f);
                unsigned bin = __float_as_uint(l) >> 20;  // 12-bit, monotone for x>=0
                atomicAdd(&hc[bin], 1u);
                atomicAdd(&hs[bin], l);
            }
        }
    }
    __syncthreads();
    for (int i = threadIdx.x; i < NBINS; i += blockDim.x) {
        if (hc[i]) {
            atomicAdd(&hist_cnt[(size_t)b * NBINS + i], hc[i]);
            atomicAdd(&hist_sum[(size_t)b * NBINS + i], hs[i]);
        }
    }
}

// K3: finalize scalar
__global__ void k_final(const double* __restrict__ fg_sum,
                        const double* __restrict__ bg_sum,
                        const u64* __restrict__ fg_cnt,
                        const unsigned int* __restrict__ hist_cnt,
                        const float* __restrict__ hist_sum,
                        int have_hist, float* __restrict__ out) {
    if (threadIdx.x != 0 || blockIdx.x != 0) return;
    double acc = 0.0;
    for (int b = 0; b < BATCH; ++b) {
        const u64 fc = fg_cnt[b];
        const u64 bg = (u64)NPIX - fc;
        u64 mk = fc > MINK ? fc : MINK;
        const u64 k = bg < mk ? bg : mk;
        double fg_term = (fc > 0) ? fg_sum[b] / (double)fc : 0.0;
        double bg_topk;
        if (k >= bg || !have_hist) {
            bg_topk = bg_sum[b];
        } else {
            u64 cnt = 0;
            double s = 0.0;
            bg_topk = 0.0;
            for (int i = NBINS - 1; i >= 0; --i) {
                unsigned c = hist_cnt[(size_t)b * NBINS + i];
                if (cnt + c >= k) {
                    double edge = (double)__uint_as_float(((unsigned)i) << 20);
                    bg_topk = s + (double)(k - cnt) * edge;
                    break;
                }
                cnt += c;
                s += (double)hist_sum[(size_t)b * NBINS + i];
            }
        }
        u64 kd = k > 1 ? k : 1;
        double bg_term = (bg > 0) ? bg_topk / (double)kd : 0.0;
        acc += fg_term + bg_term;
    }
    out[0] = (float)(acc / (double)BATCH);
}

extern "C" void kernel_launch(void* const* d_in, const int* in_sizes, int n_in,
                              void* d_out, int out_size, void* d_ws, size_t ws_size,
                              hipStream_t stream) {
    const float* x = (const float*)d_in[0];
    const int* tg = (const int*)d_in[1];
    float* out = (float*)d_out;

    char* ws = (char*)d_ws;
    double* fg_sum = (double*)ws;                    // 32 B
    double* bg_sum = (double*)(ws + 32);             // 32 B
    u64* fg_cnt = (u64*)(ws + 64);                   // 32 B
    unsigned int* hist_cnt = (unsigned int*)(ws + 128);
    float* hist_sum = (float*)(ws + 128 + (size_t)BATCH * NBINS * 4);
    const size_t need = 128 + (size_t)BATCH * NBINS * 8;
    const int have_hist = (ws_size >= need) ? 1 : 0;

    hipMemsetAsync(d_ws, 0, have_hist ? need : (size_t)128, stream);

    dim3 grid(1024, BATCH), block(256);
    k_reduce<<<grid, block, 0, stream>>>(x, tg, fg_sum, bg_sum, fg_cnt);
    if (have_hist)
        k_hist<<<grid, block, 0, stream>>>(x, tg, fg_cnt, hist_cnt, hist_sum);
    k_final<<<1, 64, 0, stream>>>(fg_sum, bg_sum, fg_cnt, hist_cnt, hist_sum, have_hist, out);
}